// Round 15
// baseline (205.042 us; speedup 1.0000x reference)
//
#include <hip/hip_runtime.h>

// GCN_72988674228318: 2-layer GCN on MI355X. R15: overlap graph build with
// gemm1 in one mega-dispatch (gemm1 emits UNSCALED X@W1; agg1 applies
// dinv[src] per edge via fused FMA). dinv buffer + calc_dinv kernel removed
// (1/sqrtf(cnt+1) inline everywhere). 5 launches total.

#define NN      50000
#define INC     128
#define HIDC    128
#define OUTC    64
#define NE      600000
#define NB      ((NN + 255) / 256)   // 196 zero blocks
#define CAP     64                   // bucket capacity per node
#define EPB     1024                 // edges per bucket block
#define EBB     ((NE + EPB - 1) / EPB)   // 586 bucket blocks

typedef unsigned short bf16_t;
typedef short bf16x8 __attribute__((ext_vector_type(8)));
typedef float f32x4  __attribute__((ext_vector_type(4)));

__device__ __forceinline__ unsigned short f2bf(float f) {
  unsigned u = __float_as_uint(f);
  u += 0x7fffu + ((u >> 16) & 1u);   // round to nearest even
  return (unsigned short)(u >> 16);
}

// ---------------- Threefry-2x32, key = (0, 42); partitionable path ---------
__device__ __forceinline__ void tf_round(unsigned &x0, unsigned &x1, int r) {
  x0 += x1;
  x1 = (x1 << r) | (x1 >> (32 - r));
  x1 ^= x0;
}

__device__ __forceinline__ void threefry_0_42(unsigned &x0, unsigned &x1) {
  const unsigned ks0 = 0u, ks1 = 42u, ks2 = 0x1BD11BDAu ^ 42u;
  x0 += ks0; x1 += ks1;
  tf_round(x0,x1,13); tf_round(x0,x1,15); tf_round(x0,x1,26); tf_round(x0,x1, 6);
  x0 += ks1; x1 += ks2 + 1u;
  tf_round(x0,x1,17); tf_round(x0,x1,29); tf_round(x0,x1,16); tf_round(x0,x1,24);
  x0 += ks2; x1 += ks0 + 2u;
  tf_round(x0,x1,13); tf_round(x0,x1,15); tf_round(x0,x1,26); tf_round(x0,x1, 6);
  x0 += ks0; x1 += ks1 + 3u;
  tf_round(x0,x1,17); tf_round(x0,x1,29); tf_round(x0,x1,16); tf_round(x0,x1,24);
  x0 += ks1; x1 += ks2 + 4u;
  tf_round(x0,x1,13); tf_round(x0,x1,15); tf_round(x0,x1,26); tf_round(x0,x1, 6);
  x0 += ks2; x1 += ks0 + 5u;
}

__device__ __forceinline__ bool keep_bit(unsigned idx) {
  unsigned x0 = 0u, x1 = idx;
  threefry_0_42(x0, x1);
  return ((x0 ^ x1) & 0x80000000u) == 0u;
}

// ---------------- prep0: zero cnt (NB blocks) + dtype detect (1 block) ------
__global__ __launch_bounds__(256)
void prep0(const unsigned* __restrict__ ew, int* __restrict__ flag,
           int* __restrict__ cnt) {
  const int b = blockIdx.x, t = threadIdx.x;
  if (b < NB) {
    int idx = b * 256 + t;
    if (idx < NN) cnt[idx] = 0;
  } else {
    __shared__ unsigned acc[256];
    unsigned v = 0;
    for (int i = t; i < 2048; i += 256) v |= ew[2 * i + 1];
    acc[t] = v;
    __syncthreads();
    for (int s = 128; s > 0; s >>= 1) {
      if (t < s) acc[t] |= acc[t + s];
      __syncthreads();
    }
    if (t == 0) *flag = (acc[0] == 0u) ? 1 : 0;   // 1 => int64
  }
}

// ---------------- mega1: bucket build (blocks 0..EBB-1) || gemm1 ------------
// gemm1: A1b = bf16(X @ W1), UNSCALED. bucket: ssrc[d*CAP+slot]=s.
__global__ __launch_bounds__(256, 3)
void mega1(const void* __restrict__ ei, const int* __restrict__ flag,
           int* __restrict__ cnt, int* __restrict__ ssrc,
           const float* __restrict__ X, const float* __restrict__ W,
           bf16_t* __restrict__ Ab, int n) {
  constexpr int K  = 128, C = HIDC, KS = 136, CT16 = C / 16;
  __shared__ bf16_t xs[64 * KS];
  __shared__ bf16_t wsT[C * KS];
  const int tid = threadIdx.x;

  if (blockIdx.x < EBB) {           // ---- bucket role ----
    const int base = blockIdx.x * EPB;
    const int isI64 = *flag;
    for (int i = tid; i < EPB; i += 256) {
      int t = base + i;
      if (t >= NE) break;
      int s, d;
      if (isI64) {
        s = (int)((const long long*)ei)[t];
        d = (int)((const long long*)ei)[NE + t];
      } else {
        s = ((const int*)ei)[t];
        d = ((const int*)ei)[NE + t];
      }
      int slot = atomicAdd(&cnt[d], 1);
      if (slot < CAP) ssrc[d * CAP + slot] = s;   // deg max ~40 << 64
    }
    return;
  }

  // ---- gemm role ----
  const int rb = (blockIdx.x - EBB) * 64;

  for (int i = tid; i < C * (K / 8); i += 256) {
    int nn = i % C, kc = i / C;
    ushort4 lo, hi;
    lo.x = f2bf(W[(size_t)(kc * 8 + 0) * C + nn]);
    lo.y = f2bf(W[(size_t)(kc * 8 + 1) * C + nn]);
    lo.z = f2bf(W[(size_t)(kc * 8 + 2) * C + nn]);
    lo.w = f2bf(W[(size_t)(kc * 8 + 3) * C + nn]);
    hi.x = f2bf(W[(size_t)(kc * 8 + 4) * C + nn]);
    hi.y = f2bf(W[(size_t)(kc * 8 + 5) * C + nn]);
    hi.z = f2bf(W[(size_t)(kc * 8 + 6) * C + nn]);
    hi.w = f2bf(W[(size_t)(kc * 8 + 7) * C + nn]);
    *(ushort4*)&wsT[nn * KS + kc * 8]     = lo;
    *(ushort4*)&wsT[nn * KS + kc * 8 + 4] = hi;
  }
  for (int i = tid; i < 64 * (K / 4); i += 256) {
    int r = i >> 5, kq = i & 31;
    int row = rb + r;
    ushort4 o = make_ushort4(0, 0, 0, 0);
    if (row < n) {
      float4 v = *(const float4*)&X[(size_t)row * K + kq * 4];
      o.x = f2bf(v.x); o.y = f2bf(v.y); o.z = f2bf(v.z); o.w = f2bf(v.w);
    }
    *(ushort4*)&xs[r * KS + kq * 4] = o;
  }
  __syncthreads();

  const int wv = tid >> 6, lane = tid & 63;
  const int m = lane & 15, q = lane >> 4;

  f32x4 acc[CT16];
#pragma unroll
  for (int c = 0; c < CT16; c++) acc[c] = (f32x4){0.f, 0.f, 0.f, 0.f};

#pragma unroll
  for (int k0 = 0; k0 < K; k0 += 32) {
    bf16x8 a = *(bf16x8*)&xs[(wv * 16 + m) * KS + k0 + q * 8];
#pragma unroll
    for (int c = 0; c < CT16; c++) {
      bf16x8 b = *(bf16x8*)&wsT[(c * 16 + m) * KS + k0 + q * 8];
      acc[c] = __builtin_amdgcn_mfma_f32_16x16x32_bf16(a, b, acc[c], 0, 0, 0);
    }
  }

  const int rowq = rb + wv * 16 + q * 4;
#pragma unroll
  for (int r = 0; r < 4; r++) {
    int row = rowq + r;
    if (row < n) {
#pragma unroll
      for (int c = 0; c < CT16; c++)
        Ab[(size_t)row * C + c * 16 + m] = f2bf(acc[c][r]);   // unscaled
    }
  }
}

__device__ __forceinline__ void acc_u2s(float4 &a, uint2 v, float s) {
  a.x = fmaf(__uint_as_float(v.x << 16),        s, a.x);
  a.y = fmaf(__uint_as_float(v.x & 0xffff0000u), s, a.y);
  a.z = fmaf(__uint_as_float(v.y << 16),        s, a.z);
  a.w = fmaf(__uint_as_float(v.y & 0xffff0000u), s, a.w);
}

__device__ __forceinline__ void acc_u2(float4 &a, uint2 v) {
  a.x += __uint_as_float(v.x << 16);
  a.y += __uint_as_float(v.x & 0xffff0000u);
  a.z += __uint_as_float(v.y << 16);
  a.w += __uint_as_float(v.y & 0xffff0000u);
}

__device__ __forceinline__ float dinv_of(int c) {
  return 1.0f / sqrtf((float)(c + 1));
}

// ---------------- agg1: half-wave/node; dinv[s] fused per edge --------------
__global__ __launch_bounds__(256)
void agg1(const bf16_t* __restrict__ A1b, const int* __restrict__ cnt,
          const int* __restrict__ ssrc, const float* __restrict__ b1,
          bf16_t* __restrict__ Hb) {
  int node = (blockIdx.x * 256 + threadIdx.x) >> 5;
  int lane = threadIdx.x & 31;
  if (node >= NN) return;

  const uint2* A4 = (const uint2*)A1b;
  const int cn = cnt[node];
  const float dn = dinv_of(cn);
  float4 acc = make_float4(0.f, 0.f, 0.f, 0.f);
  acc_u2s(acc, A4[(size_t)node * 32 + lane], dn);   // self-loop (dinv[node])
  int e = node * CAP;
  int end = e + min(cn, CAP);
  for (; e + 3 < end; e += 4) {
    int s0 = ssrc[e], s1 = ssrc[e+1], s2 = ssrc[e+2], s3 = ssrc[e+3];
    float d0 = dinv_of(cnt[s0]), d1 = dinv_of(cnt[s1]);
    float d2 = dinv_of(cnt[s2]), d3 = dinv_of(cnt[s3]);
    uint2 v0 = A4[(size_t)s0 * 32 + lane];
    uint2 v1 = A4[(size_t)s1 * 32 + lane];
    uint2 v2 = A4[(size_t)s2 * 32 + lane];
    uint2 v3 = A4[(size_t)s3 * 32 + lane];
    acc_u2s(acc, v0, d0); acc_u2s(acc, v1, d1);
    acc_u2s(acc, v2, d2); acc_u2s(acc, v3, d3);
  }
  for (; e < end; e++) {
    int s = ssrc[e];
    acc_u2s(acc, A4[(size_t)s * 32 + lane], dinv_of(cnt[s]));
  }

  int col = lane * 4;
  float4 bb = *(const float4*)&b1[col];
  float h0 = fmaxf(acc.x * dn + bb.x, 0.f);
  float h1 = fmaxf(acc.y * dn + bb.y, 0.f);
  float h2 = fmaxf(acc.z * dn + bb.z, 0.f);
  float h3 = fmaxf(acc.w * dn + bb.w, 0.f);
  unsigned base = (unsigned)node * HIDC + (unsigned)col;
  ushort4 o;
  o.x = keep_bit(base)     ? f2bf(2.f * h0) : 0;
  o.y = keep_bit(base + 1) ? f2bf(2.f * h1) : 0;
  o.z = keep_bit(base + 2) ? f2bf(2.f * h2) : 0;
  o.w = keep_bit(base + 3) ? f2bf(2.f * h3) : 0;
  ((ushort4*)Hb)[(size_t)node * 32 + lane] = o;
}

// ---------------- gemm2: A2b = bf16((Hb @ W2) * dinv[row]) ------------------
__global__ __launch_bounds__(256, 3)
void gemm2(const bf16_t* __restrict__ Hb, const float* __restrict__ W,
           const int* __restrict__ cnt, bf16_t* __restrict__ Ab, int n) {
  constexpr int K = 128, C = OUTC, KS = 136, CT16 = C / 16;
  __shared__ bf16_t xs[64 * KS];
  __shared__ bf16_t wsT[C * KS];
  const int tid = threadIdx.x;
  const int rb  = blockIdx.x * 64;

  for (int i = tid; i < C * (K / 8); i += 256) {
    int nn = i % C, kc = i / C;
    ushort4 lo, hi;
    lo.x = f2bf(W[(size_t)(kc * 8 + 0) * C + nn]);
    lo.y = f2bf(W[(size_t)(kc * 8 + 1) * C + nn]);
    lo.z = f2bf(W[(size_t)(kc * 8 + 2) * C + nn]);
    lo.w = f2bf(W[(size_t)(kc * 8 + 3) * C + nn]);
    hi.x = f2bf(W[(size_t)(kc * 8 + 4) * C + nn]);
    hi.y = f2bf(W[(size_t)(kc * 8 + 5) * C + nn]);
    hi.z = f2bf(W[(size_t)(kc * 8 + 6) * C + nn]);
    hi.w = f2bf(W[(size_t)(kc * 8 + 7) * C + nn]);
    *(ushort4*)&wsT[nn * KS + kc * 8]     = lo;
    *(ushort4*)&wsT[nn * KS + kc * 8 + 4] = hi;
  }
  for (int i = tid; i < 64 * (K / 8); i += 256) {
    int r = i >> 4, kc = i & 15;
    int row = rb + r;
    uint4 o = make_uint4(0, 0, 0, 0);
    if (row < n)
      o = *(const uint4*)(Hb + (size_t)row * K + kc * 8);
    *(uint4*)&xs[r * KS + kc * 8] = o;
  }
  __syncthreads();

  const int wv = tid >> 6, lane = tid & 63;
  const int m = lane & 15, q = lane >> 4;

  f32x4 acc[CT16];
#pragma unroll
  for (int c = 0; c < CT16; c++) acc[c] = (f32x4){0.f, 0.f, 0.f, 0.f};

#pragma unroll
  for (int k0 = 0; k0 < K; k0 += 32) {
    bf16x8 a = *(bf16x8*)&xs[(wv * 16 + m) * KS + k0 + q * 8];
#pragma unroll
    for (int c = 0; c < CT16; c++) {
      bf16x8 b = *(bf16x8*)&wsT[(c * 16 + m) * KS + k0 + q * 8];
      acc[c] = __builtin_amdgcn_mfma_f32_16x16x32_bf16(a, b, acc[c], 0, 0, 0);
    }
  }

  const int rowq = rb + wv * 16 + q * 4;
#pragma unroll
  for (int r = 0; r < 4; r++) {
    int row = rowq + r;
    if (row < n) {
      float dv = dinv_of(cnt[row]);
#pragma unroll
      for (int c = 0; c < CT16; c++)
        Ab[(size_t)row * C + c * 16 + m] = f2bf(acc[c][r] * dv);
    }
  }
}

// ---------------- agg2: quarter-wave/node + bias -> d_out -------------------
__global__ __launch_bounds__(256)
void agg2(const bf16_t* __restrict__ A2b, const int* __restrict__ cnt,
          const int* __restrict__ ssrc, const float* __restrict__ b2,
          float* __restrict__ out) {
  int node = (blockIdx.x * 256 + threadIdx.x) >> 4;
  int lane = threadIdx.x & 15;
  if (node >= NN) return;

  const uint2* A4 = (const uint2*)A2b;
  const int cn = cnt[node];
  const float dn = dinv_of(cn);
  float4 acc = make_float4(0.f, 0.f, 0.f, 0.f);
  acc_u2(acc, A4[(size_t)node * 16 + lane]);   // rows pre-scaled by dinv[row]
  int e = node * CAP;
  int end = e + min(cn, CAP);
  for (; e + 3 < end; e += 4) {
    int s0 = ssrc[e], s1 = ssrc[e+1], s2 = ssrc[e+2], s3 = ssrc[e+3];
    uint2 v0 = A4[(size_t)s0 * 16 + lane];
    uint2 v1 = A4[(size_t)s1 * 16 + lane];
    uint2 v2 = A4[(size_t)s2 * 16 + lane];
    uint2 v3 = A4[(size_t)s3 * 16 + lane];
    acc_u2(acc, v0); acc_u2(acc, v1); acc_u2(acc, v2); acc_u2(acc, v3);
  }
  for (; e < end; e++)
    acc_u2(acc, A4[(size_t)ssrc[e] * 16 + lane]);

  float4 bb = *(const float4*)&b2[lane * 4];
  ((float4*)out)[(size_t)node * 16 + lane] =
    make_float4(acc.x*dn + bb.x, acc.y*dn + bb.y, acc.z*dn + bb.z, acc.w*dn + bb.w);
}

// ---------------------------------------------------------------------------
extern "C" void kernel_launch(void* const* d_in, const int* in_sizes, int n_in,
                              void* d_out, int out_size, void* d_ws, size_t ws_size,
                              hipStream_t stream) {
  const float* x  = (const float*)d_in[0];
  const float* W1 = (const float*)d_in[1];
  const float* b1 = (const float*)d_in[2];
  const float* W2 = (const float*)d_in[3];
  const float* b2 = (const float*)d_in[4];
  const void*  ei = d_in[5];
  float* out = (float*)d_out;

  int*    flag = (int*)d_ws;               // 64
  int*    cnt  = flag + 64;                // 50048
  int*    ssrc = cnt + 50048;              // 3.2M (50000*64)
  bf16_t* A1b  = (bf16_t*)(ssrc + NN * CAP);   // 6.4M bf16
  bf16_t* Hb   = A1b + 6400000;                // 6.4M bf16
  bf16_t* A2b  = Hb + 6400000;                 // 3.2M bf16

  const int rtiles = (NN + 63) / 64;   // 782

  // 0. zero cnt + dtype detect
  prep0<<<NB + 1, 256, 0, stream>>>((const unsigned*)ei, flag, cnt);

  // 1. mega: bucket build (586 blocks) || gemm1 unscaled (782 blocks)
  mega1<<<EBB + rtiles, 256, 0, stream>>>(ei, flag, cnt, ssrc, x, W1, A1b, NN);

  // 2. agg1 (dinv fused per edge) -> Hb
  agg1<<<(NN * 32 + 255) / 256, 256, 0, stream>>>(A1b, cnt, ssrc, b1, Hb);

  // 3. layer 2
  gemm2<<<rtiles, 256, 0, stream>>>(Hb, W2, cnt, A2b, NN);
  agg2<<<(NN * 16 + 255) / 256, 256, 0, stream>>>(A2b, cnt, ssrc, b2, out);
}

// Round 16
// 189.895 us; speedup vs baseline: 1.0798x; 1.0798x over previous
//
#include <hip/hip_runtime.h>

// GCN_72988674228318: 2-layer GCN on MI355X. R16: revert R15's mega-fusion
// (57us pathological dispatch: bucket blocks held 52KB LDS + latency-bound
// atomics co-scheduled with MFMA blocks). Back to R14's proven structure
// (195us), minus calc_dinv: dinv = 1/sqrt(cnt+1) inlined at consumers.
// 6 launches: prep0, bucket_direct, gemm1, agg1, gemm2, agg2.

#define NN      50000
#define INC     128
#define HIDC    128
#define OUTC    64
#define NE      600000
#define NB      ((NN + 255) / 256)   // 196 zero blocks
#define CAP     64                   // bucket capacity per node

typedef unsigned short bf16_t;
typedef short bf16x8 __attribute__((ext_vector_type(8)));
typedef float f32x4  __attribute__((ext_vector_type(4)));

__device__ __forceinline__ unsigned short f2bf(float f) {
  unsigned u = __float_as_uint(f);
  u += 0x7fffu + ((u >> 16) & 1u);   // round to nearest even
  return (unsigned short)(u >> 16);
}

__device__ __forceinline__ float dinv_of(int c) {
  return 1.0f / sqrtf((float)(c + 1));
}

// ---------------- Threefry-2x32, key = (0, 42); partitionable path ---------
__device__ __forceinline__ void tf_round(unsigned &x0, unsigned &x1, int r) {
  x0 += x1;
  x1 = (x1 << r) | (x1 >> (32 - r));
  x1 ^= x0;
}

__device__ __forceinline__ void threefry_0_42(unsigned &x0, unsigned &x1) {
  const unsigned ks0 = 0u, ks1 = 42u, ks2 = 0x1BD11BDAu ^ 42u;
  x0 += ks0; x1 += ks1;
  tf_round(x0,x1,13); tf_round(x0,x1,15); tf_round(x0,x1,26); tf_round(x0,x1, 6);
  x0 += ks1; x1 += ks2 + 1u;
  tf_round(x0,x1,17); tf_round(x0,x1,29); tf_round(x0,x1,16); tf_round(x0,x1,24);
  x0 += ks2; x1 += ks0 + 2u;
  tf_round(x0,x1,13); tf_round(x0,x1,15); tf_round(x0,x1,26); tf_round(x0,x1, 6);
  x0 += ks0; x1 += ks1 + 3u;
  tf_round(x0,x1,17); tf_round(x0,x1,29); tf_round(x0,x1,16); tf_round(x0,x1,24);
  x0 += ks1; x1 += ks2 + 4u;
  tf_round(x0,x1,13); tf_round(x0,x1,15); tf_round(x0,x1,26); tf_round(x0,x1, 6);
  x0 += ks2; x1 += ks0 + 5u;
}

__device__ __forceinline__ bool keep_bit(unsigned idx) {
  unsigned x0 = 0u, x1 = idx;
  threefry_0_42(x0, x1);
  return ((x0 ^ x1) & 0x80000000u) == 0u;
}

// ---------------- prep0: zero cnt (NB blocks) + dtype detect (1 block) ------
__global__ __launch_bounds__(256)
void prep0(const unsigned* __restrict__ ew, int* __restrict__ flag,
           int* __restrict__ cnt) {
  const int b = blockIdx.x, t = threadIdx.x;
  if (b < NB) {
    int idx = b * 256 + t;
    if (idx < NN) cnt[idx] = 0;
  } else {
    __shared__ unsigned acc[256];
    unsigned v = 0;
    for (int i = t; i < 2048; i += 256) v |= ew[2 * i + 1];
    acc[t] = v;
    __syncthreads();
    for (int s = 128; s > 0; s >>= 1) {
      if (t < s) acc[t] |= acc[t + s];
      __syncthreads();
    }
    if (t == 0) *flag = (acc[0] == 0u) ? 1 : 0;   // 1 => int64
  }
}

// ---------------- bucket_direct: one edge pass, count + scatter -------------
__global__ __launch_bounds__(256)
void bucket_direct(const void* __restrict__ ei, const int* __restrict__ flag,
                   int* __restrict__ cnt, int* __restrict__ ssrc) {
  int t = blockIdx.x * 256 + threadIdx.x;
  if (t >= NE) return;
  int s, d;
  if (*flag) {
    s = (int)((const long long*)ei)[t];
    d = (int)((const long long*)ei)[NE + t];
  } else {
    s = ((const int*)ei)[t];
    d = ((const int*)ei)[NE + t];
  }
  int slot = atomicAdd(&cnt[d], 1);
  if (slot < CAP) ssrc[d * CAP + slot] = s;   // deg max ~40 << 64: never drops
}

// ---------------- MFMA GEMM: Ab = bf16((X @ W) * dinv[row]) -----------------
// (R12/R14-proven) 64 rows/block, all C cols. K=128. dinv inlined from cnt.
template<int C, bool IN_BF16>
__global__ __launch_bounds__(256, 3)
void gemm_mfma(const void* __restrict__ Xv, const float* __restrict__ W,
               const int* __restrict__ cnt, bf16_t* __restrict__ Ab, int n) {
  constexpr int K  = 128;
  constexpr int KS = 136;
  constexpr int CT16 = C / 16;
  __shared__ bf16_t xs[64 * KS];
  __shared__ bf16_t wsT[C * KS];

  const int tid = threadIdx.x;
  const int rb  = blockIdx.x * 64;

  for (int i = tid; i < C * (K / 8); i += 256) {
    int nn = i % C, kc = i / C;
    ushort4 lo, hi;
    lo.x = f2bf(W[(size_t)(kc * 8 + 0) * C + nn]);
    lo.y = f2bf(W[(size_t)(kc * 8 + 1) * C + nn]);
    lo.z = f2bf(W[(size_t)(kc * 8 + 2) * C + nn]);
    lo.w = f2bf(W[(size_t)(kc * 8 + 3) * C + nn]);
    hi.x = f2bf(W[(size_t)(kc * 8 + 4) * C + nn]);
    hi.y = f2bf(W[(size_t)(kc * 8 + 5) * C + nn]);
    hi.z = f2bf(W[(size_t)(kc * 8 + 6) * C + nn]);
    hi.w = f2bf(W[(size_t)(kc * 8 + 7) * C + nn]);
    *(ushort4*)&wsT[nn * KS + kc * 8]     = lo;
    *(ushort4*)&wsT[nn * KS + kc * 8 + 4] = hi;
  }
  for (int i = tid; i < 64 * (K / 4); i += 256) {
    int r = i >> 5, kq = i & 31;
    int row = rb + r;
    ushort4 o = make_ushort4(0, 0, 0, 0);
    if (row < n) {
      if (IN_BF16) {
        o = *(const ushort4*)((const bf16_t*)Xv + (size_t)row * K + kq * 4);
      } else {
        float4 v = *(const float4*)((const float*)Xv + (size_t)row * K + kq * 4);
        o.x = f2bf(v.x); o.y = f2bf(v.y); o.z = f2bf(v.z); o.w = f2bf(v.w);
      }
    }
    *(ushort4*)&xs[r * KS + kq * 4] = o;
  }
  __syncthreads();

  const int wv   = tid >> 6;
  const int lane = tid & 63;
  const int m    = lane & 15;
  const int q    = lane >> 4;

  f32x4 acc[CT16];
#pragma unroll
  for (int c = 0; c < CT16; c++) acc[c] = (f32x4){0.f, 0.f, 0.f, 0.f};

#pragma unroll
  for (int k0 = 0; k0 < K; k0 += 32) {
    bf16x8 a = *(bf16x8*)&xs[(wv * 16 + m) * KS + k0 + q * 8];
#pragma unroll
    for (int c = 0; c < CT16; c++) {
      bf16x8 b = *(bf16x8*)&wsT[(c * 16 + m) * KS + k0 + q * 8];
      acc[c] = __builtin_amdgcn_mfma_f32_16x16x32_bf16(a, b, acc[c], 0, 0, 0);
    }
  }

  const int rowq = rb + wv * 16 + q * 4;
#pragma unroll
  for (int r = 0; r < 4; r++) {
    int row = rowq + r;
    if (row < n) {
      float dv = dinv_of(cnt[row]);
#pragma unroll
      for (int c = 0; c < CT16; c++)
        Ab[(size_t)row * C + c * 16 + m] = f2bf(acc[c][r] * dv);
    }
  }
}

__device__ __forceinline__ void acc_u2(float4 &a, uint2 v) {
  a.x += __uint_as_float(v.x << 16);
  a.y += __uint_as_float(v.x & 0xffff0000u);
  a.z += __uint_as_float(v.y << 16);
  a.w += __uint_as_float(v.y & 0xffff0000u);
}

// ---------------- agg1: half-wave/node bf16 gather -> Hb (bf16) -------------
__global__ __launch_bounds__(256)
void agg1(const bf16_t* __restrict__ A1b, const int* __restrict__ cnt,
          const int* __restrict__ ssrc, const float* __restrict__ b1,
          bf16_t* __restrict__ Hb) {
  int node = (blockIdx.x * 256 + threadIdx.x) >> 5;
  int lane = threadIdx.x & 31;
  if (node >= NN) return;

  const uint2* A4 = (const uint2*)A1b;
  const int cn = cnt[node];
  const float dn = dinv_of(cn);
  float4 acc = make_float4(0.f, 0.f, 0.f, 0.f);
  acc_u2(acc, A4[(size_t)node * 32 + lane]);   // self-loop (pre-scaled rows)
  int e = node * CAP;
  int end = e + min(cn, CAP);
  for (; e + 3 < end; e += 4) {
    int s0 = ssrc[e], s1 = ssrc[e+1], s2 = ssrc[e+2], s3 = ssrc[e+3];
    uint2 v0 = A4[(size_t)s0 * 32 + lane];
    uint2 v1 = A4[(size_t)s1 * 32 + lane];
    uint2 v2 = A4[(size_t)s2 * 32 + lane];
    uint2 v3 = A4[(size_t)s3 * 32 + lane];
    acc_u2(acc, v0); acc_u2(acc, v1); acc_u2(acc, v2); acc_u2(acc, v3);
  }
  for (; e < end; e++)
    acc_u2(acc, A4[(size_t)ssrc[e] * 32 + lane]);

  int col = lane * 4;
  float4 bb = *(const float4*)&b1[col];
  float h0 = fmaxf(acc.x * dn + bb.x, 0.f);
  float h1 = fmaxf(acc.y * dn + bb.y, 0.f);
  float h2 = fmaxf(acc.z * dn + bb.z, 0.f);
  float h3 = fmaxf(acc.w * dn + bb.w, 0.f);
  unsigned base = (unsigned)node * HIDC + (unsigned)col;
  ushort4 o;
  o.x = keep_bit(base)     ? f2bf(2.f * h0) : 0;
  o.y = keep_bit(base + 1) ? f2bf(2.f * h1) : 0;
  o.z = keep_bit(base + 2) ? f2bf(2.f * h2) : 0;
  o.w = keep_bit(base + 3) ? f2bf(2.f * h3) : 0;
  ((ushort4*)Hb)[(size_t)node * 32 + lane] = o;
}

// ---------------- agg2: quarter-wave/node bf16 gather + bias -> d_out -------
__global__ __launch_bounds__(256)
void agg2(const bf16_t* __restrict__ A2b, const int* __restrict__ cnt,
          const int* __restrict__ ssrc, const float* __restrict__ b2,
          float* __restrict__ out) {
  int node = (blockIdx.x * 256 + threadIdx.x) >> 4;
  int lane = threadIdx.x & 15;
  if (node >= NN) return;

  const uint2* A4 = (const uint2*)A2b;
  const int cn = cnt[node];
  const float dn = dinv_of(cn);
  float4 acc = make_float4(0.f, 0.f, 0.f, 0.f);
  acc_u2(acc, A4[(size_t)node * 16 + lane]);
  int e = node * CAP;
  int end = e + min(cn, CAP);
  for (; e + 3 < end; e += 4) {
    int s0 = ssrc[e], s1 = ssrc[e+1], s2 = ssrc[e+2], s3 = ssrc[e+3];
    uint2 v0 = A4[(size_t)s0 * 16 + lane];
    uint2 v1 = A4[(size_t)s1 * 16 + lane];
    uint2 v2 = A4[(size_t)s2 * 16 + lane];
    uint2 v3 = A4[(size_t)s3 * 16 + lane];
    acc_u2(acc, v0); acc_u2(acc, v1); acc_u2(acc, v2); acc_u2(acc, v3);
  }
  for (; e < end; e++)
    acc_u2(acc, A4[(size_t)ssrc[e] * 16 + lane]);

  float4 bb = *(const float4*)&b2[lane * 4];
  ((float4*)out)[(size_t)node * 16 + lane] =
    make_float4(acc.x*dn + bb.x, acc.y*dn + bb.y, acc.z*dn + bb.z, acc.w*dn + bb.w);
}

// ---------------------------------------------------------------------------
extern "C" void kernel_launch(void* const* d_in, const int* in_sizes, int n_in,
                              void* d_out, int out_size, void* d_ws, size_t ws_size,
                              hipStream_t stream) {
  const float* x  = (const float*)d_in[0];
  const float* W1 = (const float*)d_in[1];
  const float* b1 = (const float*)d_in[2];
  const float* W2 = (const float*)d_in[3];
  const float* b2 = (const float*)d_in[4];
  const void*  ei = d_in[5];
  float* out = (float*)d_out;

  int*    flag = (int*)d_ws;               // 64
  int*    cnt  = flag + 64;                // 50048
  int*    ssrc = cnt + 50048;              // 3.2M (50000*64)
  bf16_t* A1b  = (bf16_t*)(ssrc + NN * CAP);   // 6.4M bf16
  bf16_t* Hb   = A1b + 6400000;                // 6.4M bf16
  bf16_t* A2b  = Hb + 6400000;                 // 3.2M bf16

  // 0. zero cnt + dtype detect (parallel blocks)
  prep0<<<NB + 1, 256, 0, stream>>>((const unsigned*)ei, flag, cnt);

  // 1. one-pass bucket build
  bucket_direct<<<(NE + 255) / 256, 256, 0, stream>>>(ei, flag, cnt, ssrc);

  const int rtiles = (NN + 63) / 64;   // 782

  // 2. layer 1
  gemm_mfma<HIDC, false><<<rtiles, 256, 0, stream>>>(x, W1, cnt, A1b, NN);
  agg1<<<(NN * 32 + 255) / 256, 256, 0, stream>>>(A1b, cnt, ssrc, b1, Hb);

  // 3. layer 2
  gemm_mfma<OUTC, true><<<rtiles, 256, 0, stream>>>(Hb, W2, cnt, A2b, NN);
  agg2<<<(NN * 16 + 255) / 256, 256, 0, stream>>>(A2b, cnt, ssrc, b2, out);
}